// Round 7
// baseline (17.814 us; speedup 1.0000x reference)
//
#include <hip/hip_runtime.h>
#include <hip/hip_bf16.h>

#define W_OUT 768
#define H_OUT 768
#define N_BOXES 128
#define ROWS 4                         // rows per band-block
#define QPT 3                          // float4 quads per thread (3*256 = 768 = 4 rows)
#define GRID1 (H_OUT / ROWS)           // 192 blocks

// Kernel 1 — one block per 4-row band. Each thread owns 3 float4 conf quads
// (12 pixels), loaded up-front (coalesced 16B/lane, single latency exposure).
// Band candidates = 128-bit ballot over register-resident boxes; candidate
// loop broadcasts box j via __shfl (no LDS staging, no sync), updates fully
// unrolled register cnt/own (compile-time indices only — no scratch).
// count==1 pixels max into 128 LDS slots; block writes its 128-slot vector
// to workspace with ONE coalesced store. Zero global atomics (R5/R6 lesson:
// 128 packed outputs = 8 cache lines ping-ponging across 8 XCD L2s ~ 10us).
__global__ __launch_bounds__(256) void band_kernel(
    const float* __restrict__ conf,
    const float* __restrict__ boxes,
    unsigned int* __restrict__ partial) {
    __shared__ unsigned int slot[N_BOXES];

    const int tid = threadIdx.x;
    const int lane = tid & 63;
    const int y0 = blockIdx.x * ROWS;

    // Conf loads first — latency hides under all the setup below.
    const float4* conf4 = (const float4*)conf;
    float4 c[QPT];
    float pyk[QPT];                    // this thread's row center per quad
    float px[QPT][4];                  // this thread's 12 pixel x-centers
#pragma unroll
    for (int k = 0; k < QPT; ++k) {
        const int i = tid + k * 256;   // linear quad index in band [0,768)
        const int r = i / 192;         // row in band (magic-mul, setup only)
        const int q = i - r * 192;     // quad within row
        c[k] = conf4[(y0 + r) * 192 + q];
        pyk[k] = (y0 + r + 0.5f) * 2.0f;            // bit-exact vs reference
#pragma unroll
        for (int j = 0; j < 4; ++j)
            px[k][j] = (q * 4 + j + 0.5f) * 2.0f;
    }

    if (tid < N_BOXES) slot[tid] = 0u;

    // Boxes in registers: lane holds boxes lane and 64+lane.
    const float4* b4 = (const float4*)boxes;
    const float4 ba = b4[lane];
    const float4 bb = b4[64 + lane];

    const float pyF = (y0 + 0.5f) * 2.0f;
    const float pyL = (y0 + ROWS - 1 + 0.5f) * 2.0f;
    const bool ia = (ba.z - ba.x) * (ba.w - ba.y) > 0.0f &&
                    ba.w >= pyF && ba.y <= pyL;
    const bool ib = (bb.z - bb.x) * (bb.w - bb.y) > 0.0f &&
                    bb.w >= pyF && bb.y <= pyL;
    const unsigned long long m0 = __ballot(ia);
    const unsigned long long m1 = __ballot(ib);

    int cnt[QPT][4], own[QPT][4];
#pragma unroll
    for (int k = 0; k < QPT; ++k)
#pragma unroll
        for (int j = 0; j < 4; ++j) { cnt[k][j] = 0; own[k][j] = 0; }

#pragma unroll 1
    for (int half = 0; half < 2; ++half) {
        unsigned long long t = half ? m1 : m0;
        const float4 src = half ? bb : ba;
        const int base = half ? 64 : 0;
        while (t) {                                  // wave-uniform loop
            const int jb = __ffsll(t) - 1;
            t &= t - 1;
            float4 o;
            o.x = __shfl(src.x, jb);                 // register broadcast
            o.y = __shfl(src.y, jb);
            o.z = __shfl(src.z, jb);
            o.w = __shfl(src.w, jb);
#pragma unroll
            for (int k = 0; k < QPT; ++k) {
                const bool by = (pyk[k] >= o.y) && (pyk[k] <= o.w);
#pragma unroll
                for (int j = 0; j < 4; ++j)
                    if (by && px[k][j] >= o.x && px[k][j] <= o.z) {
                        if (cnt[k][j] == 0) own[k][j] = base + jb;
                        cnt[k][j]++;
                    }
            }
        }
    }

    __syncthreads();                                 // slot init visible

    // Exclusive pixels -> per-box LDS max (uint order == float order, conf>=0)
    const float* cf = (const float*)c;               // c[k][j] flat, unrolled
#pragma unroll
    for (int k = 0; k < QPT; ++k) {
#pragma unroll
        for (int j = 0; j < 4; ++j)
            if (cnt[k][j] == 1)
                atomicMax(&slot[own[k][j]],
                          __float_as_uint((&c[k].x)[j]));
    }
    (void)cf;
    __syncthreads();

    if (tid < N_BOXES)
        partial[blockIdx.x * N_BOXES + tid] = slot[tid];  // one coalesced store
}

// Kernel 2 — one block per box b: max over 192 band partials (column b,
// L2-resident), reduce, one plain store. Every output element written every
// call -> harness poison overwritten, no memset needed.
__global__ __launch_bounds__(256) void reduce_kernel(
    const unsigned int* __restrict__ partial,
    float* __restrict__ scores) {
    __shared__ unsigned int wmax[4];
    const int b = blockIdx.x;
    const int tid = threadIdx.x;

    unsigned int m = (tid < GRID1) ? partial[tid * N_BOXES + b] : 0u;
    for (int off = 32; off > 0; off >>= 1) {
        const unsigned int o = (unsigned int)__shfl_xor((int)m, off);
        m = m > o ? m : o;
    }
    if ((tid & 63) == 0) wmax[tid >> 6] = m;
    __syncthreads();
    if (tid == 0) {
        unsigned int v = wmax[0];
        v = v > wmax[1] ? v : wmax[1];
        v = v > wmax[2] ? v : wmax[2];
        v = v > wmax[3] ? v : wmax[3];
        scores[b] = __uint_as_float(v);
    }
}

extern "C" void kernel_launch(void* const* d_in, const int* in_sizes, int n_in,
                              void* d_out, int out_size, void* d_ws, size_t ws_size,
                              hipStream_t stream) {
    const float* conf = (const float*)d_in[0];       // (1, 768, 768) f32
    const float* boxes = (const float*)d_in[1];      // (128, 4) f32
    float* scores = (float*)d_out;                   // (128,) f32
    unsigned int* partial = (unsigned int*)d_ws;     // 192*128*4 B = 96 KiB

    band_kernel<<<GRID1, 256, 0, stream>>>(conf, boxes, partial);
    reduce_kernel<<<N_BOXES, 256, 0, stream>>>(partial, scores);
}

// Round 8
// 14.179 us; speedup vs baseline: 1.2563x; 1.2563x over previous
//
#include <hip/hip_runtime.h>
#include <hip/hip_bf16.h>

#define W_OUT 768
#define H_OUT 768
#define N_BOXES 128
#define NCHUNK 16                      // row-chunks per box -> 2048 blocks

// Kernel 1 — one block per (box b, row-chunk). 2048 blocks x 256 thr = 8
// blocks/CU resident (32 waves/CU, full occupancy; the R3/R7 lesson: block
// count, not per-block cleverness, sets performance here). A pixel scores
// for b iff b contains it (exact float predicate) and NO other valid box
// does. Each block: ballot-build the ~2-entry overlap set (compacted to LDS
// by popcount prefix, no atomics/order dependence), scan its <=6 rows of
// b's rect with lane->x coalesced conf loads, block max-reduce, ONE store.
__global__ __launch_bounds__(256) void box_chunk_kernel(
    const float* __restrict__ conf,
    const float* __restrict__ boxes,
    unsigned int* __restrict__ partial) {
    __shared__ float4 ovl[N_BOXES];
    __shared__ float wred[4];

    const int tid = threadIdx.x;
    const int lane = tid & 63;
    const int ty = tid >> 6;
    const int b = blockIdx.x >> 4;
    const int chunk = blockIdx.x & (NCHUNK - 1);

    const float4* b4 = (const float4*)boxes;
    const float4 me = b4[b];                        // uniform -> one broadcast
    if ((me.z - me.x) * (me.w - me.y) <= 0.0f) {    // invalid -> empty mask
        if (tid == 0) partial[blockIdx.x] = 0u;
        return;
    }

    // Every thread loads its two boxes; ballots are wave-redundant.
    const float4 ba = b4[lane];
    const float4 bb = b4[64 + lane];
    const bool ia = (ba.z - ba.x) * (ba.w - ba.y) > 0.0f &&
                    ba.x <= me.z && ba.z >= me.x && ba.y <= me.w && ba.w >= me.y;
    const bool ib = (bb.z - bb.x) * (bb.w - bb.y) > 0.0f &&
                    bb.x <= me.z && bb.z >= me.x && bb.y <= me.w && bb.w >= me.y;
    unsigned long long m0 = __ballot(ia);
    unsigned long long m1 = __ballot(ib);
    if (b < 64) m0 &= ~(1ull << b);                 // exclude self
    else        m1 &= ~(1ull << (b - 64));
    const int n0 = __popcll(m0);
    const int novl = n0 + __popcll(m1);

    // Compact overlapping boxes to LDS via ballot-prefix (wave 0 only).
    if (tid < 64) {
        if (m0 & (1ull << lane))
            ovl[__popcll(m0 & ((1ull << lane) - 1))] = ba;
        if (m1 & (1ull << lane))
            ovl[n0 + __popcll(m1 & ((1ull << lane) - 1))] = bb;
    }
    __syncthreads();

    // Conservative integer bounds; exact predicate (px=2x+1 exact) inside.
    const int x0 = max(0, (int)floorf(me.x * 0.5f - 0.5f) - 1);
    const int x1 = min(W_OUT - 1, (int)ceilf(me.z * 0.5f) + 1);
    const int y0 = max(0, (int)floorf(me.y * 0.5f - 0.5f) - 1);
    const int y1 = min(H_OUT - 1, (int)ceilf(me.w * 0.5f) + 1);
    const int per = ((y1 - y0 + 1) + NCHUNK - 1) >> 4;   // rows per chunk
    const int yc0 = y0 + chunk * per;
    const int yc1 = min(y1, yc0 + per - 1);

    float lmax = 0.0f;
    for (int yy = yc0 + ty; yy <= yc1; yy += 4) {
        const float py = (yy + 0.5f) * 2.0f;
        if (py < me.y || py > me.w) continue;
        for (int xx = x0 + lane; xx <= x1; xx += 64) {
            const float px = (xx + 0.5f) * 2.0f;
            if (px < me.x || px > me.z) continue;
            bool excl = true;
            for (int k = 0; k < novl; ++k) {        // ~2 iters, LDS broadcast
                const float4 o = ovl[k];
                if (px >= o.x && px <= o.z && py >= o.y && py <= o.w) {
                    excl = false;
                    break;
                }
            }
            if (excl) lmax = fmaxf(lmax, conf[yy * W_OUT + xx]);  // coalesced
        }
    }

    for (int off = 32; off > 0; off >>= 1)
        lmax = fmaxf(lmax, __shfl_xor(lmax, off));
    if (lane == 0) wred[ty] = lmax;
    __syncthreads();
    if (tid == 0) {
        const float v = fmaxf(fmaxf(wred[0], wred[1]), fmaxf(wred[2], wred[3]));
        partial[blockIdx.x] = __float_as_uint(v);   // one plain store
    }
}

// Kernel 2 — one 256-thread block. partial is [box][chunk] (16 uints = 4
// uint4 per box). Thread t: uint4 t (box t>>2) and uint4 t+256 (box
// 64 + (t>>2)); max4 + two shfl_xor folds the 4-thread group; (t&3)==0
// stores both boxes. All 128 outputs plainly written every call.
__global__ __launch_bounds__(256) void reduce_kernel(
    const unsigned int* __restrict__ partial,
    float* __restrict__ scores) {
    const int t = threadIdx.x;
    const uint4* p4 = (const uint4*)partial;

    const uint4 a = p4[t];
    const uint4 c = p4[t + 256];
    unsigned int v1 = max(max(a.x, a.y), max(a.z, a.w));
    unsigned int v2 = max(max(c.x, c.y), max(c.z, c.w));
#pragma unroll
    for (int off = 1; off <= 2; off <<= 1) {
        const unsigned int o1 = (unsigned int)__shfl_xor((int)v1, off);
        const unsigned int o2 = (unsigned int)__shfl_xor((int)v2, off);
        v1 = v1 > o1 ? v1 : o1;
        v2 = v2 > o2 ? v2 : o2;
    }
    if ((t & 3) == 0) {
        scores[t >> 2] = __uint_as_float(v1);
        scores[64 + (t >> 2)] = __uint_as_float(v2);
    }
}

extern "C" void kernel_launch(void* const* d_in, const int* in_sizes, int n_in,
                              void* d_out, int out_size, void* d_ws, size_t ws_size,
                              hipStream_t stream) {
    const float* conf = (const float*)d_in[0];       // (1, 768, 768) f32
    const float* boxes = (const float*)d_in[1];      // (128, 4) f32
    float* scores = (float*)d_out;                   // (128,) f32
    unsigned int* partial = (unsigned int*)d_ws;     // 2048 * 4 B = 8 KiB

    box_chunk_kernel<<<N_BOXES * NCHUNK, 256, 0, stream>>>(conf, boxes, partial);
    reduce_kernel<<<1, 256, 0, stream>>>(partial, scores);
}

// Round 9
// 13.685 us; speedup vs baseline: 1.3017x; 1.0361x over previous
//
#include <hip/hip_runtime.h>
#include <hip/hip_bf16.h>

#define W_OUT 768
#define H_OUT 768
#define N_BOXES 128

// Single dispatch, no global atomics, no second kernel, no memset.
// One block (1024 thr = 16 waves) per box b: scores[b] = max conf over pixels
// contained in b and in NO other valid box. Unlike R3's version (4 waves,
// long serial row loop, dependent LDS reads -> 41us), the scan is 2D-strided
// (lane->x coalesced, 16-row y stride: <=6x2 iterations/thread) and the
// overlap set (~2 boxes, block-uniform count) is register-cached. Each block
// plainly stores its output -> poison overwritten every call, deterministic.
__global__ __launch_bounds__(1024) void box_kernel(
    const float* __restrict__ conf,
    const float* __restrict__ boxes,
    float* __restrict__ scores) {
    __shared__ float4 ovl[N_BOXES];
    __shared__ float wred[16];

    const int tid = threadIdx.x;
    const int lane = tid & 63;
    const int wv = tid >> 6;
    const int b = blockIdx.x;

    const float4* b4 = (const float4*)boxes;
    const float4 me = b4[b];                         // uniform broadcast
    if ((me.z - me.x) * (me.w - me.y) <= 0.0f) {     // invalid -> empty mask
        if (tid == 0) scores[b] = 0.0f;
        return;                                      // block-uniform exit
    }

    // Wave-redundant overlap ballot over register-resident boxes.
    const float4 ba = b4[lane];
    const float4 bb = b4[64 + lane];
    const bool ia = (ba.z - ba.x) * (ba.w - ba.y) > 0.0f &&
                    ba.x <= me.z && ba.z >= me.x && ba.y <= me.w && ba.w >= me.y;
    const bool ib = (bb.z - bb.x) * (bb.w - bb.y) > 0.0f &&
                    bb.x <= me.z && bb.z >= me.x && bb.y <= me.w && bb.w >= me.y;
    unsigned long long m0 = __ballot(ia);
    unsigned long long m1 = __ballot(ib);
    if (b < 64) m0 &= ~(1ull << b);                  // exclude self
    else        m1 &= ~(1ull << (b - 64));
    const int n0 = __popcll(m0);
    const int novl = n0 + __popcll(m1);              // block-uniform

    // Wave 0 compacts overlapping boxes to LDS (ballot-prefix, no atomics).
    if (tid < 64) {
        if (m0 & (1ull << lane))
            ovl[__popcll(m0 & ((1ull << lane) - 1))] = ba;
        if (m1 & (1ull << lane))
            ovl[n0 + __popcll(m1 & ((1ull << lane) - 1))] = bb;
    }
    __syncthreads();

    // Register-cache first 4 overlap boxes (covers ~99% of cases; rest LDS).
    float4 oreg[4];
#pragma unroll
    for (int k = 0; k < 4; ++k) {
        if (k < novl) oreg[k] = ovl[k];              // uniform branch
        else          oreg[k] = make_float4(3e30f, 3e30f, -3e30f, -3e30f);
    }

    // Conservative integer bounds; exact float predicate inside.
    const int x0 = max(0, (int)floorf(me.x * 0.5f - 0.5f) - 1);
    const int x1 = min(W_OUT - 1, (int)ceilf(me.z * 0.5f) + 1);
    const int y0 = max(0, (int)floorf(me.y * 0.5f - 0.5f) - 1);
    const int y1 = min(H_OUT - 1, (int)ceilf(me.w * 0.5f) + 1);

    float lmax = 0.0f;
    for (int yy = y0 + wv; yy <= y1; yy += 16) {
        const float py = (yy + 0.5f) * 2.0f;         // bit-exact vs reference
        const bool rowin = (py >= me.y) && (py <= me.w);
        for (int xx = x0 + lane; xx <= x1; xx += 64) {
            const float px = (xx + 0.5f) * 2.0f;
            if (!rowin || px < me.x || px > me.z) continue;
            bool hit = false;
#pragma unroll
            for (int k = 0; k < 4; ++k)
                hit |= (px >= oreg[k].x) && (px <= oreg[k].z) &&
                       (py >= oreg[k].y) && (py <= oreg[k].w);
            if (!hit && novl > 4) {                  // rare tail, uniform cnt
                for (int k = 4; k < novl && !hit; ++k) {
                    const float4 o = ovl[k];
                    hit = (px >= o.x) && (px <= o.z) &&
                          (py >= o.y) && (py <= o.w);
                }
            }
            if (!hit) lmax = fmaxf(lmax, conf[yy * W_OUT + xx]);  // coalesced
        }
    }

    // Reduce: wave butterfly -> 16 LDS slots -> wave 0 folds -> one store.
    for (int off = 32; off > 0; off >>= 1)
        lmax = fmaxf(lmax, __shfl_xor(lmax, off));
    if (lane == 0) wred[wv] = lmax;
    __syncthreads();
    if (tid < 64) {
        float v = (lane < 16) ? wred[lane] : 0.0f;
        for (int off = 8; off > 0; off >>= 1)
            v = fmaxf(v, __shfl_xor(v, off));
        if (lane == 0) scores[b] = v;
    }
}

extern "C" void kernel_launch(void* const* d_in, const int* in_sizes, int n_in,
                              void* d_out, int out_size, void* d_ws, size_t ws_size,
                              hipStream_t stream) {
    const float* conf = (const float*)d_in[0];       // (1, 768, 768) f32
    const float* boxes = (const float*)d_in[1];      // (128, 4) f32
    float* scores = (float*)d_out;                   // (128,) f32

    box_kernel<<<N_BOXES, 1024, 0, stream>>>(conf, boxes, scores);
}

// Round 10
// 12.582 us; speedup vs baseline: 1.4159x; 1.0877x over previous
//
#include <hip/hip_runtime.h>
#include <hip/hip_bf16.h>

#define W_OUT 768
#define H_OUT 768
#define N_BOXES 128

// FINAL (= round-4 best, 12.46 us): two-dispatch, atomic-free structure.
// All structural variants since (fused atomicMax finish, band blocks,
// box-chunk full-occupancy, 1024-thread single node) landed at 12.5-14.2 us:
// the harness graph-replay floor (~12-13 us) dominates once kernel time is
// below it (R3: a 41 us kernel showed only 0.35 us overhead). This version
// had the best measured time and the shortest critical path per block.
//
// Kernel 1 — one block per image row (768 blocks x 256 threads = 12 waves/CU).
// Each thread owns 3 pixels (x = tid, tid+256, tid+512). Row candidates =
// 128-bit ballot mask (valid && y-contains-row), ~7 bits set. Box-outer/
// pixel-inner: one wave-uniform LDS broadcast per candidate tests all 3
// pixels. count==1 pixels max into 128 per-block LDS slots (LDS atomics,
// uint bit-order == float order for conf>=0). Block writes its 128-slot
// row-max vector coalesced to workspace. Zero global atomics (R1/R5/R6
// lesson: 128 packed outputs = 8 cache lines ping-ponging across XCD L2s).
__global__ __launch_bounds__(256) void row_owner_kernel(
    const float* __restrict__ conf,
    const float* __restrict__ boxes,
    float* __restrict__ partial) {
    __shared__ float4 sbox[N_BOXES];
    __shared__ unsigned int slot[N_BOXES];
    __shared__ unsigned long long masks[2];

    const int tid = threadIdx.x;
    const int y = blockIdx.x;

    // Issue the row's conf loads first — HBM latency hides under LDS setup.
    const float* crow = conf + y * W_OUT;
    const float c0 = crow[tid];
    const float c1 = crow[tid + 256];
    const float c2 = crow[tid + 512];

    const float4* b4 = (const float4*)boxes;
    if (tid < N_BOXES) {
        float4 o = b4[tid];
        sbox[tid] = o;
        slot[tid] = 0u;
        const float py = (y + 0.5f) * 2.0f;          // bit-exact vs reference
        bool in = (o.z - o.x) * (o.w - o.y) > 0.0f && py >= o.y && py <= o.w;
        unsigned long long m = __ballot(in);          // waves 0,1 fully active
        if ((tid & 63) == 0) masks[tid >> 6] = m;
    }
    __syncthreads();

    const unsigned long long m0 = masks[0];
    const unsigned long long m1 = masks[1];

    const float px0 = (tid + 0.5f) * 2.0f;
    const float px1 = (tid + 256 + 0.5f) * 2.0f;
    const float px2 = (tid + 512 + 0.5f) * 2.0f;
    int cnt0 = 0, cnt1 = 0, cnt2 = 0;
    int own0 = -1, own1 = -1, own2 = -1;

    unsigned long long t = m0;
    while (t) {
        int j = __ffsll(t) - 1; t &= t - 1;
        float4 o = sbox[j];                           // uniform -> broadcast
        if (px0 >= o.x && px0 <= o.z) { cnt0++; if (own0 < 0) own0 = j; }
        if (px1 >= o.x && px1 <= o.z) { cnt1++; if (own1 < 0) own1 = j; }
        if (px2 >= o.x && px2 <= o.z) { cnt2++; if (own2 < 0) own2 = j; }
    }
    t = m1;
    while (t) {
        int j = __ffsll(t) - 1; t &= t - 1;
        float4 o = sbox[64 + j];
        if (px0 >= o.x && px0 <= o.z) { cnt0++; if (own0 < 0) own0 = 64 + j; }
        if (px1 >= o.x && px1 <= o.z) { cnt1++; if (own1 < 0) own1 = 64 + j; }
        if (px2 >= o.x && px2 <= o.z) { cnt2++; if (own2 < 0) own2 = 64 + j; }
    }

    if (cnt0 == 1) atomicMax(&slot[own0], __float_as_uint(c0));
    if (cnt1 == 1) atomicMax(&slot[own1], __float_as_uint(c1));
    if (cnt2 == 1) atomicMax(&slot[own2], __float_as_uint(c2));
    __syncthreads();

    if (tid < N_BOXES)
        partial[y * N_BOXES + tid] = __uint_as_float(slot[tid]);
}

// Kernel 2 — one block per box: max over the 768 per-row partials (column b
// of the 768x128 workspace, L2-resident), block max-reduce, one plain store.
// All 128 outputs written every call -> harness poison overwritten.
__global__ __launch_bounds__(256) void reduce_kernel(
    const float* __restrict__ partial,
    float* __restrict__ scores) {
    __shared__ float wmax[4];
    const int b = blockIdx.x;
    const int tid = threadIdx.x;

    float m = fmaxf(fmaxf(partial[tid * N_BOXES + b],
                          partial[(tid + 256) * N_BOXES + b]),
                    partial[(tid + 512) * N_BOXES + b]);
    for (int off = 32; off > 0; off >>= 1)
        m = fmaxf(m, __shfl_xor(m, off));
    if ((tid & 63) == 0) wmax[tid >> 6] = m;
    __syncthreads();
    if (tid == 0)
        scores[b] = fmaxf(fmaxf(wmax[0], wmax[1]), fmaxf(wmax[2], wmax[3]));
}

extern "C" void kernel_launch(void* const* d_in, const int* in_sizes, int n_in,
                              void* d_out, int out_size, void* d_ws, size_t ws_size,
                              hipStream_t stream) {
    const float* conf = (const float*)d_in[0];     // (1, 768, 768) f32
    const float* boxes = (const float*)d_in[1];    // (128, 4) f32
    float* scores = (float*)d_out;                 // (128,) f32
    float* partial = (float*)d_ws;                 // 768*128*4 B = 384 KiB

    row_owner_kernel<<<H_OUT, 256, 0, stream>>>(conf, boxes, partial);
    reduce_kernel<<<N_BOXES, 256, 0, stream>>>(partial, scores);
}